// Round 14
// baseline (34.162 us; speedup 1.0000x reference)
//
#include <hip/hip_runtime.h>
#include <math.h>

#define Ee 100
#define Hh 64
#define Bb 64
#define Tt 20
#define Kk 50
#define NQUADS 4032
#define BBLK 320             // basket blocks: 5 per b (4 t's each)
#define QBLK 512
#define NBLK (BBLK + QBLK)   // 832

// LDS float offsets (basket role). AP aliases rcT after the task phase.
#define O_ACT  0        // [100][52]  acT[e*52+k]
#define O_RCT  5200     // [100][52]
#define O_AP   5200     // [51][52] alias (row 0 = zeros, rows 1..50 = prefix)
#define O_A0T  10400    // [100][4]   a0T[e*4+tl]
#define O_R0T  10800    // [100][4]
#define O_TH   11200    // [100]
#define O_GA   11300    // [100]
#define O_KESC 11400    // [52]
#define O_RDAT 11452    // [4][52]
#define O_RAT  11660    // [4][52]
#define O_KES0 11868    // [4]
#define O_SELF 11872    // [4]
#define O_IIS  11876    // 50 int
#define O_IID  11926    // 4 int
#define O_RED  11930    // 4
#define LDSF   11936    // 47744 B -> 3 blocks/CU

__device__ __forceinline__ float wave_sum(float v) {
    #pragma unroll
    for (int m = 32; m >= 1; m >>= 1) v += __shfl_xor(v, m, 64);
    return v;
}
__device__ __forceinline__ float rl(float v, int l) {
    return __uint_as_float(__builtin_amdgcn_readlane(__float_as_uint(v), l));
}

__global__ __launch_bounds__(256) void k_fused(
    const float* __restrict__ alpha, const float* __restrict__ rho,
    const float* __restrict__ lam,   const float* __restrict__ beta,
    const float* __restrict__ mu_tab,const float* __restrict__ theta,
    const float* __restrict__ gamma_,const float* __restrict__ w1,
    const float* __restrict__ b1,    const float* __restrict__ w2,
    const float* __restrict__ b2,    const float* __restrict__ sigma_list,
    const float* __restrict__ prices,const float* __restrict__ price_table,
    const int* __restrict__ item_ids,const int* __restrict__ itemset,
    const int* __restrict__ userid,
    float* __restrict__ partial)
{
    __shared__ float buf[LDSF];
    const int tid  = threadIdx.x;
    const int lane = tid & 63;
    const int wid  = tid >> 6;

    if (blockIdx.x < BBLK) {
        // ======================= basket role =======================
        const int b = blockIdx.x / 5;
        const int tbase = (blockIdx.x % 5) * 4;
        int* iisS = (int*)&buf[O_IIS];
        int* iidS = (int*)&buf[O_IID];
        const long uid = userid[b];

        if (tid < Kk) iisS[tid] = itemset[b*Kk + tid];
        else if (tid >= 56 && tid < 60) iidS[tid-56] = item_ids[b*Tt + tbase + (tid-56)];
        if (tid >= 64 && tid < 89)
            *(float4*)&buf[O_TH + 4*(tid-64)] = *(const float4*)&theta[uid*Ee + 4*(tid-64)];
        else if (tid >= 96 && tid < 121)
            *(float4*)&buf[O_GA + 4*(tid-96)] = *(const float4*)&gamma_[uid*Ee + 4*(tid-96)];
        __syncthreads();

        // gather ac/rc transposed (once per block)
        for (int i = tid; i < 2500; i += 256) {
            int half = (i < 1250) ? 0 : 1;
            int ii = i - half*1250;
            int k = ii % Kk, c = ii / Kk;
            long idx = iisS[k];
            float4 v = *(const float4*)((half ? rho : alpha) + idx*Ee + 4*c);
            float* dst = &buf[half ? O_RCT : O_ACT];
            dst[(4*c+0)*52+k] = v.x; dst[(4*c+1)*52+k] = v.y;
            dst[(4*c+2)*52+k] = v.z; dst[(4*c+3)*52+k] = v.w;
        }
        // gather a0/r0 for the 4 t's
        for (int i = tid; i < 200; i += 256) {
            int half = (i < 100) ? 0 : 1;
            int ii = i - half*100;
            int tl = ii & 3, c = ii >> 2;
            long idx = iidS[tl];
            float4 v = *(const float4*)((half ? rho : alpha) + idx*Ee + 4*c);
            float* dst = &buf[half ? O_R0T : O_A0T];
            dst[(4*c+0)*4+tl] = v.x; dst[(4*c+1)*4+tl] = v.y;
            dst[(4*c+2)*4+tl] = v.z; dst[(4*c+3)*4+tl] = v.w;
        }
        __syncthreads();

        #define KESC_TASK(KK_)                                                     \
        {   int k_ = (KK_);                                                        \
            long idx_ = iisS[k_];                                                  \
            const float* lp_ = lam  + idx_*Ee;                                     \
            const float* bp_ = beta + idx_*Ee;                                     \
            float ml_=0.f, mtha_=0.f, mgb_=0.f;                                    \
            for (int c = 0; c < 25; ++c) {                                         \
                float4 l4 = *(const float4*)(lp_ + 4*c);                           \
                float4 b4 = *(const float4*)(bp_ + 4*c);                           \
                float4 t4 = *(const float4*)&buf[O_TH + 4*c];                      \
                float4 g4 = *(const float4*)&buf[O_GA + 4*c];                      \
                ml_  += (l4.x + l4.y) + (l4.z + l4.w);                             \
                mgb_ += g4.x*b4.x + g4.y*b4.y + g4.z*b4.z + g4.w*b4.w;             \
                mtha_ += t4.x*buf[O_ACT + (4*c+0)*52 + k_]                         \
                       + t4.y*buf[O_ACT + (4*c+1)*52 + k_]                         \
                       + t4.z*buf[O_ACT + (4*c+2)*52 + k_]                         \
                       + t4.w*buf[O_ACT + (4*c+3)*52 + k_];                        \
            }                                                                      \
            buf[O_KESC + k_] = 0.01f*(ml_ + mtha_) - 0.01f*mgb_*logf(price_table[idx_]); \
        }
        #define KES0_TASK(TT_)                                                     \
        {   int t_ = (TT_);                                                        \
            long idx_ = iidS[t_];                                                  \
            const float* lp_ = lam  + idx_*Ee;                                     \
            const float* bp_ = beta + idx_*Ee;                                     \
            float self_=0.f, ml_=0.f, mtha_=0.f, mgb_=0.f;                         \
            for (int c = 0; c < 25; ++c) {                                         \
                float4 l4 = *(const float4*)(lp_ + 4*c);                           \
                float4 b4 = *(const float4*)(bp_ + 4*c);                           \
                float4 t4 = *(const float4*)&buf[O_TH + 4*c];                      \
                float4 g4 = *(const float4*)&buf[O_GA + 4*c];                      \
                float a0_ = buf[O_A0T + (4*c+0)*4 + t_], a1_ = buf[O_A0T + (4*c+1)*4 + t_]; \
                float a2_ = buf[O_A0T + (4*c+2)*4 + t_], a3_ = buf[O_A0T + (4*c+3)*4 + t_]; \
                float r0_ = buf[O_R0T + (4*c+0)*4 + t_], r1_ = buf[O_R0T + (4*c+1)*4 + t_]; \
                float r2_ = buf[O_R0T + (4*c+2)*4 + t_], r3_ = buf[O_R0T + (4*c+3)*4 + t_]; \
                self_ += a0_*r0_ + a1_*r1_ + a2_*r2_ + a3_*r3_;                    \
                ml_  += (l4.x + l4.y) + (l4.z + l4.w);                             \
                mtha_ += t4.x*a0_ + t4.y*a1_ + t4.z*a2_ + t4.w*a3_;                \
                mgb_ += g4.x*b4.x + g4.y*b4.y + g4.z*b4.z + g4.w*b4.w;             \
            }                                                                      \
            buf[O_SELF + t_] = self_;                                              \
            buf[O_KES0 + t_] = 0.01f*(ml_ + mtha_) - 0.01f*mgb_*logf(prices[b*Tt + tbase + t_]); \
        }

        // ---- task phase: A-tile (regs), rda/ra0c, kesc, kes0 ----
        float accA[4][4] = {{0.f}};
        int k0 = 0, j0A = 0;
        if (tid < 169) {
            int kt = tid / 13, jt = tid - kt*13;
            k0 = 4*kt; j0A = 4*jt;
            #pragma unroll 2
            for (int e = 0; e < Ee; ++e) {
                float4 a4 = *(const float4*)&buf[O_ACT + e*52 + k0];
                float4 r4 = *(const float4*)&buf[O_RCT + e*52 + j0A];
                accA[0][0]=fmaf(a4.x,r4.x,accA[0][0]); accA[0][1]=fmaf(a4.x,r4.y,accA[0][1]);
                accA[0][2]=fmaf(a4.x,r4.z,accA[0][2]); accA[0][3]=fmaf(a4.x,r4.w,accA[0][3]);
                accA[1][0]=fmaf(a4.y,r4.x,accA[1][0]); accA[1][1]=fmaf(a4.y,r4.y,accA[1][1]);
                accA[1][2]=fmaf(a4.y,r4.z,accA[1][2]); accA[1][3]=fmaf(a4.y,r4.w,accA[1][3]);
                accA[2][0]=fmaf(a4.z,r4.x,accA[2][0]); accA[2][1]=fmaf(a4.z,r4.y,accA[2][1]);
                accA[2][2]=fmaf(a4.z,r4.z,accA[2][2]); accA[2][3]=fmaf(a4.z,r4.w,accA[2][3]);
                accA[3][0]=fmaf(a4.w,r4.x,accA[3][0]); accA[3][1]=fmaf(a4.w,r4.y,accA[3][1]);
                accA[3][2]=fmaf(a4.w,r4.z,accA[3][2]); accA[3][3]=fmaf(a4.w,r4.w,accA[3][3]);
            }
        } else if (tid < 221) {
            int t2 = tid - 169;
            int tl = t2 / 13, jq = t2 - tl*13;
            int j0 = 4*jq;
            float p0=0.f,p1=0.f,p2=0.f,p3=0.f, q0=0.f,q1=0.f,q2=0.f,q3=0.f;
            #pragma unroll 4
            for (int e = 0; e < Ee; ++e) {
                float a0v = buf[O_A0T + e*4 + tl];
                float r0v = buf[O_R0T + e*4 + tl];
                float4 r4 = *(const float4*)&buf[O_RCT + e*52 + j0];
                float4 a4 = *(const float4*)&buf[O_ACT + e*52 + j0];
                p0 = fmaf(r4.x, a0v, p0); p1 = fmaf(r4.y, a0v, p1);
                p2 = fmaf(r4.z, a0v, p2); p3 = fmaf(r4.w, a0v, p3);
                q0 = fmaf(r0v, a4.x, q0); q1 = fmaf(r0v, a4.y, q1);
                q2 = fmaf(r0v, a4.z, q2); q3 = fmaf(r0v, a4.w, q3);
            }
            int jm = Kk - j0; if (jm > 4) jm = 4;
            buf[O_RDAT + tl*52 + j0+0] = p0; buf[O_RAT + tl*52 + j0+0] = q0;
            buf[O_RDAT + tl*52 + j0+1] = p1; buf[O_RAT + tl*52 + j0+1] = q1;
            if (jm > 2) {
                buf[O_RDAT + tl*52 + j0+2] = p2; buf[O_RAT + tl*52 + j0+2] = q2;
                buf[O_RDAT + tl*52 + j0+3] = p3; buf[O_RAT + tl*52 + j0+3] = q3;
            }
        } else {
            KESC_TASK(tid - 221)          // k = 0..34
        }
        if (tid < 19) {
            int task2 = 256 + tid;        // 256..274
            if (task2 < 271) { KESC_TASK(task2 - 221) }   // k = 35..49
            else             { KES0_TASK(task2 - 271) }   // t = 0..3
        }
        __syncthreads();   // all rcT readers done; safe to overwrite with AP

        // ---- write A into AP rows 1..50; zero row 0 ----
        if (tid < 169) {
            #pragma unroll
            for (int a = 0; a < 4; ++a)
                #pragma unroll
                for (int c = 0; c < 4; ++c)
                    if (k0+a < Kk && j0A+c < Kk)
                        buf[O_AP + (1+k0+a)*52 + j0A+c] = accA[a][c];
        } else if (tid < 221) {
            buf[O_AP + (tid - 169)] = 0.f;    // row 0, 52 cols
        }
        __syncthreads();

        // ---- in-place prefix: AP[k] += AP[k-1], k=1..50 (wave 0) ----
        if (wid == 0 && lane < Kk) {
            #pragma unroll 5
            for (int k = 1; k <= Kk; ++k)
                buf[O_AP + k*52 + lane] += buf[O_AP + (k-1)*52 + lane];
        }
        __syncthreads();

        // ---- per-wave t: closed-form p_t + b128 j-loop (A,P via row differencing) ----
        const int t = tbase + wid;
        const bool valid = lane < Kk;
        const int item = iidS[wid];
        bool eq = valid && (iisS[lane] == item);
        unsigned long long mq = __ballot(eq);
        int p_t = mq ? (int)__ffsll((long long)mq) - 1 : -1;
        const int pr = (p_t < 0) ? 0 : p_t;

        float raj    = valid ? buf[O_RAT  + wid*52 + lane] : 0.f;
        float rj_own = valid ? buf[O_RDAT + wid*52 + lane] : 0.f;
        float kc_own = valid ? buf[O_KESC + lane] : 0.f;

        float pv = raj;
        #pragma unroll
        for (int off = 1; off <= 32; off <<= 1) {
            float u = __shfl_up(pv, off, 64);
            if (lane >= off) pv += u;
        }
        float rasub = (p_t >= 0) ? rl(raj, p_t) : 0.f;
        const float cumra = pv - ((p_t >= 0 && lane >= p_t) ? rasub : 0.f);

        const int   sub_le = (p_t >= 0 && p_t <= lane) ? 1 : 0;
        const float len    = (float)(lane + 2 - sub_le);
        const float invden = 1.f / ((len + 1.f) * 100.f);
        const float invlen = 1.f / (100.f * len);
        const float subf   = (p_t >= 0 && lane >= p_t) ? 1.f : 0.f;

        const int lc = valid ? lane : (Kk-1);
        float max0 = -3e38f, maxc = -3e38f, diag = 0.f;

        #define PROC(JJ, P1_, P0_, Q1_, Q0_, R_, K_)                   \
        {   const int j = (JJ);                                        \
            float Tc = Q1_ - Q0_;                                      \
            float Ac = P1_ - P0_;                                      \
            float Cum = fmaf(-subf, Tc, P1_);                          \
            float v0 = fmaf(fmaf(2.f, R_, Cum), invden, K_);           \
            float vc = fmaf(Cum + R_ + Ac, invden, K_);                \
            bool elig = (j > lane) && (j != p_t) && (j < Kk);          \
            max0 = elig ? fmaxf(max0, v0) : max0;                      \
            maxc = elig ? fmaxf(maxc, vc) : maxc;                      \
            if (j == lc) diag = Cum; }

        #pragma unroll
        for (int jq = 0; jq < 13; ++jq) {
            const int j0 = 4*jq;
            float4 P1 = *(const float4*)&buf[O_AP + (lc+1)*52 + j0];   // own row
            float4 P0 = *(const float4*)&buf[O_AP + lc*52     + j0];   // own row
            float4 Q1 = *(const float4*)&buf[O_AP + (pr+1)*52 + j0];   // broadcast
            float4 Q0 = *(const float4*)&buf[O_AP + pr*52     + j0];   // broadcast
            float4 Rq = *(const float4*)&buf[O_RDAT + wid*52  + j0];   // broadcast
            float4 Kq = *(const float4*)&buf[O_KESC + j0];             // broadcast
            PROC(j0+0, P1.x, P0.x, Q1.x, Q0.x, Rq.x, Kq.x)
            PROC(j0+1, P1.y, P0.y, Q1.y, Q0.y, Rq.y, Kq.y)
            PROC(j0+2, P1.z, P0.z, Q1.z, Q0.z, Rq.z, Kq.z)
            PROC(j0+3, P1.w, P0.w, Q1.w, Q0.w, Rq.w, Kq.w)
        }
        #undef PROC

        const float look0 = fmaxf(0.f, max0);
        const float lookc = fmaxf(0.f, maxc);
        const float Kes0 = buf[O_KES0 + wid] + fmaf(buf[O_SELF + wid] + cumra, invlen, look0);
        const float KesC = kc_own + fmaf(rj_own + diag, invlen, lookc);
        const float x = Kes0 - KesC;
        const float term = (x >= 0.f) ? -log1pf(expf(-x)) : (x - log1pf(expf(x)));
        const float contrib = (valid && lane != p_t) ? term : 0.f;
        float s = wave_sum(contrib);
        if (lane == 0) buf[O_RED + wid] = s;
        __syncthreads();
        if (tid == 0)
            partial[blockIdx.x] = buf[O_RED] + buf[O_RED+1] + buf[O_RED+2] + buf[O_RED+3];
        #undef KESC_TASK
        #undef KES0_TASK
    } else {
        // ======================= qprior role (r13, unchanged) =======================
        float* w1s = buf;
        float* red = buf + 6400;

        for (int i = tid; i < Hh*Ee/4; i += 256)
            *(float4*)&w1s[4*i] = *(const float4*)&w1[4*i];
        __syncthreads();

        const float w2j = w2[lane];
        const float b1j = b1[lane];
        const float b2v = b2[0];
        const float c0 = -0.5f/sigma_list[0], c1 = -0.5f/sigma_list[1];
        const float c2 = -0.5f/sigma_list[2], c3 = -0.5f/sigma_list[3];
        const float c4 = -0.5f/sigma_list[4], c5 = -0.5f/sigma_list[5];
        const float c6 = -0.5f/sigma_list[6];

        const bool ldA = (lane < 25);
        const bool ldB = (lane >= 32) && (lane < 57);
        const int  lq  = ldA ? (lane<<2) : ((lane-32)<<2);
        const int  wave = (blockIdx.x - BBLK)*4 + wid;   // 0..2047

        #define LOAD_QUAD(Q, AB, CD, CF)                                          \
        {                                                                         \
            int r4_ = 4*(Q);                                                      \
            const float* tab_; int4 ii_;                                          \
            if (r4_ < 16000) {                                                    \
                int seg_ = r4_/3200;                                              \
                ii_ = *(const int4*)&itemset[r4_ - seg_*3200];                    \
                tab_ = (seg_==0)?alpha:(seg_==1)?rho:(seg_==2)?lam                \
                      :(seg_==3)?beta:mu_tab;                                     \
                CF = (seg_==0)?c0:(seg_==1)?c1:(seg_==2)?c2:(seg_==3)?c3:c4;      \
            } else if (r4_ < 16064) {                                             \
                ii_ = *(const int4*)&userid[r4_-16000]; tab_ = theta;  CF = c5;   \
            } else {                                                              \
                ii_ = *(const int4*)&userid[r4_-16064]; tab_ = gamma_; CF = c6;   \
            }                                                                     \
            if (ldA) {                                                            \
                AB = *(const float4*)(tab_ + (long)ii_.x*Ee + lq);                \
                CD = *(const float4*)(tab_ + (long)ii_.z*Ee + lq);                \
            } else if (ldB) {                                                     \
                AB = *(const float4*)(tab_ + (long)ii_.y*Ee + lq);                \
                CD = *(const float4*)(tab_ + (long)ii_.w*Ee + lq);                \
            }                                                                     \
        }

        float ssacc = 0.f, qacc = 0.f;
        float4 curAB = make_float4(0.f,0.f,0.f,0.f);
        float4 curCD = make_float4(0.f,0.f,0.f,0.f);
        float  ccur = 0.f;
        int qd = wave;
        if (qd < NQUADS) LOAD_QUAD(qd, curAB, curCD, ccur);

        while (qd < NQUADS) {
            float4 nAB = make_float4(0.f,0.f,0.f,0.f);
            float4 nCD = make_float4(0.f,0.f,0.f,0.f);
            float  cnx = 0.f;
            int qn = qd + QBLK*4;
            if (qn < NQUADS) LOAD_QUAD(qn, nAB, nCD, cnx);

            if (ldA || ldB)
                ssacc += ccur * (curAB.x*curAB.x + curAB.y*curAB.y
                               + curAB.z*curAB.z + curAB.w*curAB.w
                               + curCD.x*curCD.x + curCD.y*curCD.y
                               + curCD.z*curCD.z + curCD.w*curCD.w);

            float hA0=b1j, hA1=0.f, hB0=b1j, hB1=0.f;
            float hC0=b1j, hC1=0.f, hD0=b1j, hD1=0.f;
            #pragma unroll
            for (int i = 0; i < 25; ++i) {
                float4 wv = *(const float4*)&w1s[lane*Ee + 4*i];
                hA0 = fmaf(rl(curAB.x, i),    wv.x, hA0);
                hA1 = fmaf(rl(curAB.y, i),    wv.y, hA1);
                hA0 = fmaf(rl(curAB.z, i),    wv.z, hA0);
                hA1 = fmaf(rl(curAB.w, i),    wv.w, hA1);
                hB0 = fmaf(rl(curAB.x, 32+i), wv.x, hB0);
                hB1 = fmaf(rl(curAB.y, 32+i), wv.y, hB1);
                hB0 = fmaf(rl(curAB.z, 32+i), wv.z, hB0);
                hB1 = fmaf(rl(curAB.w, 32+i), wv.w, hB1);
                hC0 = fmaf(rl(curCD.x, i),    wv.x, hC0);
                hC1 = fmaf(rl(curCD.y, i),    wv.y, hC1);
                hC0 = fmaf(rl(curCD.z, i),    wv.z, hC0);
                hC1 = fmaf(rl(curCD.w, i),    wv.w, hC1);
                hD0 = fmaf(rl(curCD.x, 32+i), wv.x, hD0);
                hD1 = fmaf(rl(curCD.y, 32+i), wv.y, hD1);
                hD0 = fmaf(rl(curCD.z, 32+i), wv.z, hD0);
                hD1 = fmaf(rl(curCD.w, 32+i), wv.w, hD1);
            }
            float vA = fmaxf(hA0+hA1, 0.f)*w2j;
            float vB = fmaxf(hB0+hB1, 0.f)*w2j;
            float vC = fmaxf(hC0+hC1, 0.f)*w2j;
            float vD = fmaxf(hD0+hD1, 0.f)*w2j;
            #pragma unroll
            for (int m = 32; m >= 1; m >>= 1) {
                vA += __shfl_xor(vA, m, 64);
                vB += __shfl_xor(vB, m, 64);
                vC += __shfl_xor(vC, m, 64);
                vD += __shfl_xor(vD, m, 64);
            }
            qacc -= 1.f/(1.f+expf(-(vA+b2v))) + 1.f/(1.f+expf(-(vB+b2v)))
                  + 1.f/(1.f+expf(-(vC+b2v))) + 1.f/(1.f+expf(-(vD+b2v)));

            curAB = nAB; curCD = nCD; ccur = cnx; qd = qn;
        }
        #undef LOAD_QUAD

        float s = wave_sum(ssacc);
        if (lane == 0) red[wid] = s + qacc;
        __syncthreads();
        if (tid == 0)
            partial[blockIdx.x] = red[0]+red[1]+red[2]+red[3];
    }
}

// ---------- kernel 2: deterministic final reduce ----------
__global__ __launch_bounds__(256) void k_final(
    const float* __restrict__ p, int n, float* __restrict__ out)
{
    __shared__ double sh[256];
    double s = 0.0;
    for (int i = threadIdx.x; i < n; i += 256) s += (double)p[i];
    sh[threadIdx.x] = s;
    __syncthreads();
    for (int m = 128; m >= 1; m >>= 1) {
        if (threadIdx.x < m) sh[threadIdx.x] += sh[threadIdx.x + m];
        __syncthreads();
    }
    if (threadIdx.x == 0) out[0] = (float)sh[0];
}

// ---------- launch ----------
extern "C" void kernel_launch(void* const* d_in, const int* in_sizes, int n_in,
                              void* d_out, int out_size, void* d_ws, size_t ws_size,
                              hipStream_t stream) {
    const float* alpha      = (const float*)d_in[0];
    const float* rho        = (const float*)d_in[1];
    const float* lam        = (const float*)d_in[2];
    const float* beta       = (const float*)d_in[3];
    const float* mu_tab     = (const float*)d_in[4];
    const float* theta      = (const float*)d_in[5];
    const float* gamma_     = (const float*)d_in[6];
    const float* w1         = (const float*)d_in[7];
    const float* b1         = (const float*)d_in[8];
    const float* w2         = (const float*)d_in[9];
    const float* b2         = (const float*)d_in[10];
    const float* sigma_list = (const float*)d_in[11];
    // d_in[12] = mu_list (zeros; folded out)
    const float* prices      = (const float*)d_in[13];
    const float* price_table = (const float*)d_in[14];
    const int*   item_ids    = (const int*)d_in[15];
    const int*   itemset     = (const int*)d_in[16];
    const int*   userid      = (const int*)d_in[17];

    float* ws = (float*)d_ws;   // partial[NBLK]

    k_fused<<<NBLK, 256, 0, stream>>>(
        alpha, rho, lam, beta, mu_tab, theta, gamma_,
        w1, b1, w2, b2, sigma_list, prices, price_table,
        item_ids, itemset, userid, ws);
    k_final<<<1, 256, 0, stream>>>(ws, NBLK, (float*)d_out);
}

// Round 15
// 31.801 us; speedup vs baseline: 1.0742x; 1.0742x over previous
//
#include <hip/hip_runtime.h>
#include <math.h>

#define Ee 100
#define Hh 64
#define Bb 64
#define Tt 20
#define Kk 50
#define NROWS 16128
#define NQUADS 4032
#define PREBLKS 256
#define QBLKS   512
#define NB3 (Bb*Tt)              // 1280 partials (written by 320 blocks x 4 waves)
#define APAD 52                  // padded A row stride (16B-aligned)

// ---------- helpers ----------
__device__ __forceinline__ float wave_sum(float v) {
    #pragma unroll
    for (int m = 32; m >= 1; m >>= 1) v += __shfl_xor(v, m, 64);
    return v;
}
__device__ __forceinline__ float rl(float v, int l) {
    return __uint_as_float(__builtin_amdgcn_readlane(__float_as_uint(v), l));
}

// ---------- kernel A: fused {per-b precompute (4 blocks/b)} + {qprior} ----------
__global__ __launch_bounds__(256) void k_fused1(
    const float* __restrict__ alpha, const float* __restrict__ rho,
    const float* __restrict__ lam,   const float* __restrict__ beta,
    const float* __restrict__ mu_tab,const float* __restrict__ theta,
    const float* __restrict__ gamma_,const float* __restrict__ w1,
    const float* __restrict__ b1,    const float* __restrict__ w2,
    const float* __restrict__ b2,    const float* __restrict__ sigma_list,
    const float* __restrict__ prices,const float* __restrict__ price_table,
    const int* __restrict__ item_ids,const int* __restrict__ itemset,
    const int* __restrict__ userid,
    float* __restrict__ A, float* __restrict__ rda0, float* __restrict__ ra0c,
    float* __restrict__ kesc, float* __restrict__ kes0, float* __restrict__ rda0self,
    float* __restrict__ partialQ)
{
    __shared__ float buf[12260];
    const int tid  = threadIdx.x;
    const int lane = tid & 63;
    const int wid  = tid >> 6;

    if (blockIdx.x < PREBLKS) {
        float* acT = buf;            // [100][52]
        float* rcT = buf + 5200;     // [100][52]
        float* a0T = buf + 10400;    // [100][8]
        float* r0T = buf + 11200;    // [100][8]
        float* th  = buf + 12000;    // 100
        float* ga  = buf + 12100;    // 100
        int*   iis = (int*)&buf[12200];  // 50
        int*   iid5= (int*)&buf[12252];  // 5

        const int b = blockIdx.x >> 2, q = blockIdx.x & 3;
        const int kcnt = (q < 2) ? 13 : 12;
        const int kbeg = q*12 + ((q < 2) ? q : 2);
        const int tbeg = q*5;
        const long uid = userid[b];

        if (tid < Kk) iis[tid] = itemset[b*Kk + tid];
        else if (tid >= 56 && tid < 61) iid5[tid-56] = item_ids[b*Tt + tbeg + (tid-56)];
        for (int i = tid; i < Ee; i += 256) {
            th[i] = theta[uid*Ee+i];
            ga[i] = gamma_[uid*Ee+i];
        }
        __syncthreads();

        for (int i = tid; i < 2500; i += 256) {
            int half = (i < 1250) ? 0 : 1;
            int ii = i - half*1250;
            int k = ii % Kk, c = ii / Kk;
            long idx = iis[k];
            float4 v = *(const float4*)((half ? rho : alpha) + idx*Ee + 4*c);
            float* dst = half ? rcT : acT;
            dst[(4*c+0)*52+k] = v.x; dst[(4*c+1)*52+k] = v.y;
            dst[(4*c+2)*52+k] = v.z; dst[(4*c+3)*52+k] = v.w;
        }
        for (int i = tid; i < 250; i += 256) {
            int half = (i < 125) ? 0 : 1;
            int ii = i - half*125;
            int tl = ii % 5, c = ii / 5;
            long idx = iid5[tl];
            float4 v = *(const float4*)((half ? rho : alpha) + idx*Ee + 4*c);
            float* dst = half ? r0T : a0T;
            dst[(4*c+0)*8+tl] = v.x; dst[(4*c+1)*8+tl] = v.y;
            dst[(4*c+2)*8+tl] = v.z; dst[(4*c+3)*8+tl] = v.w;
        }
        __syncthreads();

        if (tid < kcnt*13) {
            int k = kbeg + tid/13, jt = tid - (tid/13)*13, j0 = 4*jt;
            float s0=0.f, s1=0.f, s2=0.f, s3=0.f;
            #pragma unroll 4
            for (int e = 0; e < Ee; ++e) {
                float a  = acT[e*52 + k];
                float4 r = *(const float4*)&rcT[e*52 + j0];
                s0 = fmaf(a, r.x, s0); s1 = fmaf(a, r.y, s1);
                s2 = fmaf(a, r.z, s2); s3 = fmaf(a, r.w, s3);
            }
            // padded A: row stride 52, 16B-aligned -> single float4 store
            *(float4*)(A + ((long)b*Kk + k)*APAD + j0) = make_float4(s0, s1, s2, s3);
        } else if (tid < kcnt*13 + 65) {
            int t2 = tid - kcnt*13;
            int tl = t2/13, jt = t2 - 13*tl, j0 = 4*jt;
            float p0=0.f,p1=0.f,p2=0.f,p3=0.f, q0=0.f,q1=0.f,q2=0.f,q3=0.f;
            #pragma unroll 4
            for (int e = 0; e < Ee; ++e) {
                float a0v = a0T[e*8 + tl];
                float r0v = r0T[e*8 + tl];
                float4 r = *(const float4*)&rcT[e*52 + j0];
                float4 a = *(const float4*)&acT[e*52 + j0];
                p0 = fmaf(r.x, a0v, p0); p1 = fmaf(r.y, a0v, p1);
                p2 = fmaf(r.z, a0v, p2); p3 = fmaf(r.w, a0v, p3);
                q0 = fmaf(r0v, a.x, q0); q1 = fmaf(r0v, a.y, q1);
                q2 = fmaf(r0v, a.z, q2); q3 = fmaf(r0v, a.w, q3);
            }
            int t = tbeg + tl;
            float* d1 = rda0 + ((long)b*Tt + t)*Kk + j0;
            float* d2 = ra0c + ((long)b*Tt + t)*Kk + j0;
            d1[0]=p0; d1[1]=p1; d2[0]=q0; d2[1]=q1;
            if (jt < 12) { d1[2]=p2; d1[3]=p3; d2[2]=q2; d2[3]=q3; }
        }

        for (int task = wid; task < 5 + kcnt; task += 4) {
            if (task < 5) {
                int tl = task, t = tbeg + tl;
                long idx = iid5[tl];
                float s=0.f, ml=0.f, mtha=0.f, mgb=0.f;
                if (lane < Kk) {
                    #pragma unroll
                    for (int u = 0; u < 2; ++u) {
                        int e = lane + u*Kk;
                        float a0v = a0T[e*8+tl], r0v = r0T[e*8+tl];
                        s    = fmaf(r0v, a0v, s);
                        ml  += lam[idx*Ee+e];
                        mtha = fmaf(th[e], a0v, mtha);
                        mgb  = fmaf(ga[e], beta[idx*Ee+e], mgb);
                    }
                }
                s = wave_sum(s); ml = wave_sum(ml); mtha = wave_sum(mtha); mgb = wave_sum(mgb);
                if (lane == 0) {
                    rda0self[b*Tt+t] = s;
                    kes0[b*Tt+t] = 0.01f*ml + 0.01f*mtha - 0.01f*mgb*logf(prices[b*Tt+t]);
                }
            } else {
                int k = kbeg + (task - 5);
                long idx = iis[k];
                float ml=0.f, mtha=0.f, mgb=0.f;
                if (lane < Kk) {
                    #pragma unroll
                    for (int u = 0; u < 2; ++u) {
                        int e = lane + u*Kk;
                        ml  += lam[idx*Ee+e];
                        mtha = fmaf(th[e], acT[e*52+k], mtha);
                        mgb  = fmaf(ga[e], beta[idx*Ee+e], mgb);
                    }
                }
                ml = wave_sum(ml); mtha = wave_sum(mtha); mgb = wave_sum(mgb);
                if (lane == 0)
                    kesc[b*Kk+k] = 0.01f*ml + 0.01f*mtha - 0.01f*mgb*logf(price_table[idx]);
            }
        }
    } else {
        float* w1s = buf;
        float* red = buf + 6400;

        for (int i = tid; i < Hh*Ee/4; i += 256)
            *(float4*)&w1s[4*i] = *(const float4*)&w1[4*i];
        __syncthreads();

        const float w2j = w2[lane];
        const float b1j = b1[lane];
        const float b2v = b2[0];
        const float c0 = -0.5f/sigma_list[0], c1 = -0.5f/sigma_list[1];
        const float c2 = -0.5f/sigma_list[2], c3 = -0.5f/sigma_list[3];
        const float c4 = -0.5f/sigma_list[4], c5 = -0.5f/sigma_list[5];
        const float c6 = -0.5f/sigma_list[6];

        const bool ldA = (lane < 25);
        const bool ldB = (lane >= 32) && (lane < 57);
        const int  lq  = ldA ? (lane<<2) : ((lane-32)<<2);
        const int  wave = (blockIdx.x - PREBLKS)*4 + wid;

        #define LOAD_QUAD(Q, AB, CD, CF)                                          \
        {                                                                         \
            int r4_ = 4*(Q);                                                      \
            const float* tab_; int4 ii_;                                          \
            if (r4_ < 16000) {                                                    \
                int seg_ = r4_/3200;                                              \
                ii_ = *(const int4*)&itemset[r4_ - seg_*3200];                    \
                tab_ = (seg_==0)?alpha:(seg_==1)?rho:(seg_==2)?lam                \
                      :(seg_==3)?beta:mu_tab;                                     \
                CF = (seg_==0)?c0:(seg_==1)?c1:(seg_==2)?c2:(seg_==3)?c3:c4;      \
            } else if (r4_ < 16064) {                                             \
                ii_ = *(const int4*)&userid[r4_-16000]; tab_ = theta;  CF = c5;   \
            } else {                                                              \
                ii_ = *(const int4*)&userid[r4_-16064]; tab_ = gamma_; CF = c6;   \
            }                                                                     \
            if (ldA) {                                                            \
                AB = *(const float4*)(tab_ + (long)ii_.x*Ee + lq);                \
                CD = *(const float4*)(tab_ + (long)ii_.z*Ee + lq);                \
            } else if (ldB) {                                                     \
                AB = *(const float4*)(tab_ + (long)ii_.y*Ee + lq);                \
                CD = *(const float4*)(tab_ + (long)ii_.w*Ee + lq);                \
            }                                                                     \
        }

        float ssacc = 0.f, qacc = 0.f;
        float4 curAB = make_float4(0.f,0.f,0.f,0.f);
        float4 curCD = make_float4(0.f,0.f,0.f,0.f);
        float  ccur = 0.f;
        int qd = wave;
        if (qd < NQUADS) LOAD_QUAD(qd, curAB, curCD, ccur);

        while (qd < NQUADS) {
            float4 nAB = make_float4(0.f,0.f,0.f,0.f);
            float4 nCD = make_float4(0.f,0.f,0.f,0.f);
            float  cnx = 0.f;
            int qn = qd + QBLKS*4;
            if (qn < NQUADS) LOAD_QUAD(qn, nAB, nCD, cnx);

            if (ldA || ldB)
                ssacc += ccur * (curAB.x*curAB.x + curAB.y*curAB.y
                               + curAB.z*curAB.z + curAB.w*curAB.w
                               + curCD.x*curCD.x + curCD.y*curCD.y
                               + curCD.z*curCD.z + curCD.w*curCD.w);

            float hA0=b1j, hA1=0.f, hB0=b1j, hB1=0.f;
            float hC0=b1j, hC1=0.f, hD0=b1j, hD1=0.f;
            #pragma unroll
            for (int i = 0; i < 25; ++i) {
                float4 wv = *(const float4*)&w1s[lane*Ee + 4*i];
                hA0 = fmaf(rl(curAB.x, i),    wv.x, hA0);
                hA1 = fmaf(rl(curAB.y, i),    wv.y, hA1);
                hA0 = fmaf(rl(curAB.z, i),    wv.z, hA0);
                hA1 = fmaf(rl(curAB.w, i),    wv.w, hA1);
                hB0 = fmaf(rl(curAB.x, 32+i), wv.x, hB0);
                hB1 = fmaf(rl(curAB.y, 32+i), wv.y, hB1);
                hB0 = fmaf(rl(curAB.z, 32+i), wv.z, hB0);
                hB1 = fmaf(rl(curAB.w, 32+i), wv.w, hB1);
                hC0 = fmaf(rl(curCD.x, i),    wv.x, hC0);
                hC1 = fmaf(rl(curCD.y, i),    wv.y, hC1);
                hC0 = fmaf(rl(curCD.z, i),    wv.z, hC0);
                hC1 = fmaf(rl(curCD.w, i),    wv.w, hC1);
                hD0 = fmaf(rl(curCD.x, 32+i), wv.x, hD0);
                hD1 = fmaf(rl(curCD.y, 32+i), wv.y, hD1);
                hD0 = fmaf(rl(curCD.z, 32+i), wv.z, hD0);
                hD1 = fmaf(rl(curCD.w, 32+i), wv.w, hD1);
            }
            float vA = fmaxf(hA0+hA1, 0.f)*w2j;
            float vB = fmaxf(hB0+hB1, 0.f)*w2j;
            float vC = fmaxf(hC0+hC1, 0.f)*w2j;
            float vD = fmaxf(hD0+hD1, 0.f)*w2j;
            #pragma unroll
            for (int m = 32; m >= 1; m >>= 1) {
                vA += __shfl_xor(vA, m, 64);
                vB += __shfl_xor(vB, m, 64);
                vC += __shfl_xor(vC, m, 64);
                vD += __shfl_xor(vD, m, 64);
            }
            qacc -= 1.f/(1.f+expf(-(vA+b2v))) + 1.f/(1.f+expf(-(vB+b2v)))
                  + 1.f/(1.f+expf(-(vC+b2v))) + 1.f/(1.f+expf(-(vD+b2v)));

            curAB = nAB; curCD = nCD; ccur = cnx; qd = qn;
        }
        #undef LOAD_QUAD

        float s = wave_sum(ssacc);
        if (lane == 0) red[wid] = s + qacc;
        __syncthreads();
        if (tid == 0)
            partialQ[blockIdx.x - PREBLKS] = red[0]+red[1]+red[2]+red[3];
    }
}

// ---------- kernel B: 320 blocks x 4 waves; aligned A copy, closed-form p_t, b128 phase-2 ----------
__global__ __launch_bounds__(256) void k_main(
    const float* __restrict__ A, const float* __restrict__ rda0,
    const float* __restrict__ ra0c, const float* __restrict__ kesc,
    const float* __restrict__ kes0, const float* __restrict__ rda0self,
    const int* __restrict__ item_ids, const int* __restrict__ itemset,
    float* __restrict__ partial)
{
    __shared__ float Als[Kk*52];     // stride 52, 16B-aligned rows
    __shared__ float Pls[Kk*52];
    __shared__ float rdat[4][52];
    __shared__ float kescs[52];
    __shared__ int   iisS[Kk];
    __shared__ int   iidS[4];

    const int bk = blockIdx.x;
    const int b  = bk / 5;
    const int tbase = (bk % 5) * 4;
    const int tid = threadIdx.x;
    const int lane = tid & 63, wid = tid >> 6;
    const int t  = tbase + wid;
    const int bt = b*Tt + t;

    // stage A -> Als: straight aligned float4 copy (A already padded [50][52])
    for (int i = tid; i < 650; i += 256)
        *(float4*)&Als[4*i] = *(const float4*)&A[(long)b*(Kk*APAD) + 4*i];
    if (tid < Kk) iisS[tid] = itemset[b*Kk + tid];
    else if (tid < Kk + 4) iidS[tid - Kk] = item_ids[b*Tt + tbase + (tid - Kk)];

    const bool valid = lane < Kk;
    const float rj_own = valid ? rda0[(long)bt*Kk + lane] : 0.f;
    const float kc_own = valid ? kesc[b*Kk + lane] : 0.f;
    const float raj    = valid ? ra0c[(long)bt*Kk + lane] : 0.f;
    if (valid) { rdat[wid][lane] = rj_own; kescs[lane] = kc_own; }
    __syncthreads();

    // P build: wave 0, lanes 0..49, per-column serial prefix
    if (wid == 0 && lane < Kk) {
        float s = 0.f;
        #pragma unroll 5
        for (int k = 0; k < Kk; ++k) {
            s += Als[k*52 + lane];
            Pls[k*52 + lane] = s;
        }
    }
    __syncthreads();

    const int item = iidS[wid];
    bool eq = valid && (iisS[lane] == item);
    unsigned long long mq = __ballot(eq);
    int p_t = mq ? (int)__ffsll((long long)mq) - 1 : -1;
    const int pr = (p_t < 0) ? 0 : p_t;

    float pv = raj;
    #pragma unroll
    for (int off = 1; off <= 32; off <<= 1) {
        float u = __shfl_up(pv, off, 64);
        if (lane >= off) pv += u;
    }
    float rasub = (p_t >= 0) ? rl(raj, p_t) : 0.f;
    const float cumra = pv - ((p_t >= 0 && lane >= p_t) ? rasub : 0.f);

    const int   sub_le = (p_t >= 0 && p_t <= lane) ? 1 : 0;
    const float len    = (float)(lane + 2 - sub_le);
    const float invden = 1.f / ((len + 1.f) * 100.f);
    const float invlen = 1.f / (100.f * len);
    const float subf   = (p_t >= 0 && lane >= p_t) ? 1.f : 0.f;

    const int lc = valid ? lane : (Kk-1);
    float max0 = -3e38f, maxc = -3e38f, diag = 0.f;

    #define PROC(JJ, P_, A_, T_, R_, K_)                               \
    {   const int j = (JJ);                                            \
        float Cum = fmaf(-subf, T_, P_);                               \
        float v0 = fmaf(fmaf(2.f, R_, Cum), invden, K_);               \
        float vc = fmaf(Cum + R_ + A_, invden, K_);                    \
        bool elig = (j > lane) && (j != p_t) && (j < Kk);              \
        max0 = elig ? fmaxf(max0, v0) : max0;                          \
        maxc = elig ? fmaxf(maxc, vc) : maxc;                          \
        if (j == lc) diag = Cum; }

    #pragma unroll
    for (int jq = 0; jq < 13; ++jq) {
        const int j0 = 4*jq;
        float4 Pq = *(const float4*)&Pls[lc*52 + j0];   // own row
        float4 Aq = *(const float4*)&Als[lc*52 + j0];   // own row
        float4 Tq = *(const float4*)&Als[pr*52 + j0];   // broadcast
        float4 Rq = *(const float4*)&rdat[wid][j0];     // broadcast
        float4 Kq = *(const float4*)&kescs[j0];         // broadcast
        PROC(j0+0, Pq.x, Aq.x, Tq.x, Rq.x, Kq.x)
        PROC(j0+1, Pq.y, Aq.y, Tq.y, Rq.y, Kq.y)
        PROC(j0+2, Pq.z, Aq.z, Tq.z, Rq.z, Kq.z)
        PROC(j0+3, Pq.w, Aq.w, Tq.w, Rq.w, Kq.w)
    }
    #undef PROC

    const float look0 = fmaxf(0.f, max0);
    const float lookc = fmaxf(0.f, maxc);
    const float Kes0 = kes0[bt] + fmaf(rda0self[bt] + cumra, invlen, look0);
    const float KesC = kc_own   + fmaf(rj_own + diag,        invlen, lookc);
    const float x = Kes0 - KesC;
    const float term = (x >= 0.f) ? -log1pf(expf(-x)) : (x - log1pf(expf(x)));
    const float contrib = (valid && lane != p_t) ? term : 0.f;
    float s = wave_sum(contrib);
    if (lane == 0) partial[bt] = s;
}

// ---------- kernel C: deterministic final reduce ----------
__global__ __launch_bounds__(256) void k_final(
    const float* __restrict__ p1, int n1,
    const float* __restrict__ p3, int n3,
    float* __restrict__ out)
{
    __shared__ double sh[256];
    double s = 0.0;
    for (int i = threadIdx.x; i < n1; i += 256) s += (double)p1[i];
    for (int i = threadIdx.x; i < n3; i += 256) s += (double)p3[i];
    sh[threadIdx.x] = s;
    __syncthreads();
    for (int m = 128; m >= 1; m >>= 1) {
        if (threadIdx.x < m) sh[threadIdx.x] += sh[threadIdx.x + m];
        __syncthreads();
    }
    if (threadIdx.x == 0) out[0] = (float)sh[0];
}

// ---------- launch ----------
extern "C" void kernel_launch(void* const* d_in, const int* in_sizes, int n_in,
                              void* d_out, int out_size, void* d_ws, size_t ws_size,
                              hipStream_t stream) {
    const float* alpha      = (const float*)d_in[0];
    const float* rho        = (const float*)d_in[1];
    const float* lam        = (const float*)d_in[2];
    const float* beta       = (const float*)d_in[3];
    const float* mu_tab     = (const float*)d_in[4];
    const float* theta      = (const float*)d_in[5];
    const float* gamma_     = (const float*)d_in[6];
    const float* w1         = (const float*)d_in[7];
    const float* b1         = (const float*)d_in[8];
    const float* w2         = (const float*)d_in[9];
    const float* b2         = (const float*)d_in[10];
    const float* sigma_list = (const float*)d_in[11];
    // d_in[12] = mu_list (zeros; folded out)
    const float* prices      = (const float*)d_in[13];
    const float* price_table = (const float*)d_in[14];
    const int*   item_ids    = (const int*)d_in[15];
    const int*   itemset     = (const int*)d_in[16];
    const int*   userid      = (const int*)d_in[17];

    float* ws = (float*)d_ws;
    const size_t offA    = 0;                           // B*K*52 (padded)
    const size_t offRDA  = offA   + (size_t)Bb*Kk*APAD; // B*T*K
    const size_t offRA0C = offRDA + (size_t)Bb*Tt*Kk;   // B*T*K
    const size_t offKESC = offRA0C+ (size_t)Bb*Tt*Kk;   // B*K
    const size_t offKES0 = offKESC+ (size_t)Bb*Kk;      // B*T
    const size_t offSELF = offKES0+ (size_t)Bb*Tt;      // B*T
    const size_t offP1   = offSELF+ (size_t)Bb*Tt;      // QBLKS
    const size_t offP3   = offP1  + QBLKS;              // NB3

    k_fused1<<<PREBLKS + QBLKS, 256, 0, stream>>>(
        alpha, rho, lam, beta, mu_tab, theta, gamma_,
        w1, b1, w2, b2, sigma_list, prices, price_table,
        item_ids, itemset, userid,
        ws + offA, ws + offRDA, ws + offRA0C,
        ws + offKESC, ws + offKES0, ws + offSELF,
        ws + offP1);
    k_main<<<Bb*5, 256, 0, stream>>>(ws + offA, ws + offRDA, ws + offRA0C,
                                     ws + offKESC, ws + offKES0, ws + offSELF,
                                     item_ids, itemset, ws + offP3);
    k_final<<<1, 256, 0, stream>>>(ws + offP1, QBLKS, ws + offP3, NB3, (float*)d_out);
}